// Round 10
// baseline (160.272 us; speedup 1.0000x reference)
//
#include <hip/hip_runtime.h>
#include <hip/hip_bf16.h>

#define S_LEN   2048
#define D_MODEL 1024
#define NH      16
#define DK      64
#define BATCH   2
#define M_ROWS  (BATCH * S_LEN)   // 4096
#define QT      128               // attention query tile
#define LDP     72                // Q staging stride (bf16 elems)
#define LDP2    136               // Ps stride (68 words; 4-banks/row step -> ~2-way)
#define LDV2    130               // Vt stride (65 words; 8-rows-apart = 8 mod 32 -> 2-way)
#define LDW     132               // GEMM epilogue LDS stride

typedef __attribute__((ext_vector_type(8))) short bf16x8;
typedef __attribute__((ext_vector_type(4))) float f32x4;
typedef __attribute__((ext_vector_type(8))) unsigned short us8;
typedef __attribute__((ext_vector_type(4))) unsigned short us4;

static __device__ __forceinline__ unsigned short f2bf(float f) {
    unsigned u = __builtin_bit_cast(unsigned, f);
    u += 0x7fffu + ((u >> 16) & 1u);   // RNE
    return (unsigned short)(u >> 16);
}

// ---------------------------------------------------------------------------
// All fp32->bf16 conversions in ONE launch. dst = xb | Wq | Wk | Wv | Wo.
// ---------------------------------------------------------------------------
__global__ __launch_bounds__(256) void cvt_all(const float* __restrict__ x,
                                               const float* __restrict__ wq,
                                               const float* __restrict__ wk,
                                               const float* __restrict__ wv,
                                               const float* __restrict__ wo,
                                               unsigned short* __restrict__ dst) {
    const int b = blockIdx.x;
    if (b < 2048) {
        const size_t o8 = (size_t)b * 256 + threadIdx.x;
        const float4* s = (const float4*)x + o8 * 2;
        float4 a = s[0], bb = s[1];
        us8 o;
        o[0] = f2bf(a.x);  o[1] = f2bf(a.y);  o[2] = f2bf(a.z);  o[3] = f2bf(a.w);
        o[4] = f2bf(bb.x); o[5] = f2bf(bb.y); o[6] = f2bf(bb.z); o[7] = f2bf(bb.w);
        *((us8*)dst + o8) = o;
    } else {
        const int wi = (b - 2048) >> 9;
        const float* src = (wi == 0) ? wq : (wi == 1) ? wk : (wi == 2) ? wv : wo;
        const size_t local = (size_t)((b - 2048) & 511) * 256 + threadIdx.x;
        const float4* s = (const float4*)src + local * 2;
        float4 a = s[0], bb = s[1];
        us8 o;
        o[0] = f2bf(a.x);  o[1] = f2bf(a.y);  o[2] = f2bf(a.z);  o[3] = f2bf(a.w);
        o[4] = f2bf(bb.x); o[5] = f2bf(bb.y); o[6] = f2bf(bb.z); o[7] = f2bf(bb.w);
        *((us8*)dst + 524288 + (size_t)wi * 131072 + local) = o;
    }
}

// ---------------------------------------------------------------------------
// MFMA GEMM (B-transposed): unchanged from round 9 (passing).
// ---------------------------------------------------------------------------
template <int STORE_BF16, int BN>
__global__ __launch_bounds__(256) void mfma_gemm_bt(const unsigned short* __restrict__ A,
                                                    const unsigned short* __restrict__ W,
                                                    void* __restrict__ Cv, int N) {
    constexpr int K = 1024, BM = 128, BK = 64;
    constexpr int MI = (BN == 128) ? 4 : 2;
    constexpr int SMEM = (STORE_BF16 && BN == 128) ? (128 * LDW)
                                                   : (BM * BK + BN * BK);
    __shared__ unsigned short smem[SMEM];
    unsigned short* As = smem;               // [BM][BK]
    unsigned short* Bs = smem + BM * BK;     // [BN][BK]

    const int tid  = threadIdx.x;
    const int w    = tid >> 6;
    const int lane = tid & 63;
    const int m0 = blockIdx.y * BM;
    const int n0 = blockIdx.x * BN;
    const int wr = (BN == 128) ? (w >> 1) * 64 : w * 32;
    const int wc = (BN == 128) ? (w & 1) * 64 : 0;

    const int srow   = lane >> 3;                          // 0..7
    const int schunk = ((lane & 7) ^ (lane >> 3)) * 8;     // swizzled k-chunk (elems)
    const int sw = lane & 7;
    const int c0 = (((lane >> 4) + 0) ^ sw) * 8;           // kk = 0 read offset
    const int c1 = (((lane >> 4) + 4) ^ sw) * 8;           // kk = 32 read offset

    f32x4 acc[MI][4] = {};

    for (int k0 = 0; k0 < K; k0 += BK) {
        __syncthreads();
#pragma unroll
        for (int t = 0; t < 4; ++t) {                      // A: 16 groups, 4/wave
            const int rbase = w * 32 + t * 8;
            const unsigned short* ga = A + (size_t)(m0 + rbase + srow) * K + k0 + schunk;
            __builtin_amdgcn_global_load_lds(
                (const __attribute__((address_space(1))) void*)ga,
                (__attribute__((address_space(3))) void*)(As + rbase * BK), 16, 0, 0);
        }
#pragma unroll
        for (int t = 0; t < BN / 32; ++t) {                // B: wave stride BN/4
            const int rbase = w * (BN / 4) + t * 8;
            const unsigned short* gb = W + (size_t)(n0 + rbase + srow) * K + k0 + schunk;
            __builtin_amdgcn_global_load_lds(
                (const __attribute__((address_space(1))) void*)gb,
                (__attribute__((address_space(3))) void*)(Bs + rbase * BK), 16, 0, 0);
        }
        __syncthreads();

        const int fr = lane & 15;
#pragma unroll
        for (int kk = 0; kk < 2; ++kk) {
            const int co = kk ? c1 : c0;
            bf16x8 af[MI], bfr[4];
#pragma unroll
            for (int i = 0; i < MI; ++i)
                af[i] = *(const bf16x8*)(As + (wr + i * 16 + fr) * BK + co);
#pragma unroll
            for (int j = 0; j < 4; ++j)
                bfr[j] = *(const bf16x8*)(Bs + (wc + j * 16 + fr) * BK + co);
#pragma unroll
            for (int i = 0; i < MI; ++i)
#pragma unroll
                for (int j = 0; j < 4; ++j)
                    acc[i][j] = __builtin_amdgcn_mfma_f32_16x16x32_bf16(af[i], bfr[j], acc[i][j], 0, 0, 0);
        }
    }

    const int col = lane & 15;
    const int rq  = (lane >> 4) * 4;

    if constexpr (STORE_BF16 && BN == 128) {
        __syncthreads();
#pragma unroll
        for (int i = 0; i < 4; ++i)
#pragma unroll
            for (int j = 0; j < 4; ++j)
#pragma unroll
                for (int r = 0; r < 4; ++r)
                    smem[(wr + i * 16 + rq + r) * LDW + wc + j * 16 + col] = f2bf(acc[i][j][r]);
        __syncthreads();
#pragma unroll
        for (int e = 0; e < 8; ++e) {
            const int idx = e * 256 + tid;
            const int row = idx >> 4;
            const int cc  = (idx & 15) * 8;
            us4 lo = *(const us4*)(smem + row * LDW + cc);
            us4 hi = *(const us4*)(smem + row * LDW + cc + 4);
            us8 v;
            v[0] = lo[0]; v[1] = lo[1]; v[2] = lo[2]; v[3] = lo[3];
            v[4] = hi[0]; v[5] = hi[1]; v[6] = hi[2]; v[7] = hi[3];
            *(us8*)((unsigned short*)Cv + (size_t)(m0 + row) * N + n0 + cc) = v;
        }
    } else {
#pragma unroll
        for (int i = 0; i < MI; ++i)
#pragma unroll
            for (int j = 0; j < 4; ++j)
#pragma unroll
                for (int r = 0; r < 4; ++r) {
                    const int gm = m0 + wr + i * 16 + rq + r;
                    const int gn = n0 + wc + j * 16 + col;
                    if (STORE_BF16)
                        ((unsigned short*)Cv)[(size_t)gm * N + gn] = f2bf(acc[i][j][r]);
                    else
                        ((float*)Cv)[(size_t)gm * N + gn] = acc[i][j][r];
                }
    }
}

// ---------------------------------------------------------------------------
// MFMA sliding-window ALiBi attention v3 (round 10):
//  - 128-query tile x 3 chunks of 128 keys (span [q0-128, q0+256) tight).
//  - Grid (h, b, q-tile): linear id = h + 16b + 32qt -> XCD = h mod 8, so all
//    q-tiles of a (h,b) slice share one XCD; slice working set ~3 MB fits L2.
//  - Wave w owns q rows [32w, 32w+32) as 2 m-tiles of 16.
//  - K staged via global_load_lds + XOR-chunk swizzle (wave stride 32 rows).
//  - V transposed into Vt[d][key] stride 130 (2-way writes = free).
//  - Fixed-m softmax (m = slope*min(qpos,128)+12), P -> Ps (overlays Q
//    staging buffer), PV with Vt B-frags. 64 MFMAs/wave per barrier pair.
//  - LDS 67.8 KB -> 2 blocks/CU (= grid 512 / 256 CUs).
// ---------------------------------------------------------------------------
__global__ __launch_bounds__(256) void attn_mfma(const unsigned short* __restrict__ qkvb,
                                                 const float* __restrict__ slopes,
                                                 unsigned short* __restrict__ aoutb) {
    __shared__ unsigned short QPs[QT * LDP2];   // Q staging (stride LDP), then Ps (stride LDP2)
    __shared__ unsigned short Ks[QT * 64];      // unpadded, chunk-swizzled
    __shared__ unsigned short Vt[64 * LDV2];    // [d][key 0..127]

    const int tid  = threadIdx.x;
    const int w    = tid >> 6;
    const int lane = tid & 63;
    const int h  = blockIdx.x;
    const int b  = blockIdx.y;
    const int q0 = blockIdx.z * QT;
    const float slope = slopes[h];
    const size_t rowbase = (size_t)b * S_LEN * 3072;

    // Stage Q tile: 128 rows x 8 us8 chunks = 1024; 4 per thread (stride LDP).
#pragma unroll
    for (int e = 0; e < 4; ++e) {
        int idx = e * 256 + tid;
        int r = idx >> 3, cc = (idx & 7) * 8;
        us8 v = *(const us8*)(qkvb + rowbase + (size_t)(q0 + r) * 3072 + h * DK + cc);
        *(us8*)(QPs + r * LDP + cc) = v;
    }

    const int col = lane & 15;
    const int rq  = (lane >> 4) * 4;
    const int wq  = w * 32;                 // wave's q-offset (2 m-tiles of 16)
    const int fo  = (lane >> 4) * 8;

    // K staging / frag-read swizzle constants.
    const int srowK   = lane >> 3;                         // 0..7
    const int schunkK = ((lane & 7) ^ srowK) * 8;
    const int kc0 = (((lane >> 4) + 0) ^ (lane & 7)) * 8;
    const int kc1 = (((lane >> 4) + 4) ^ (lane & 7)) * 8;

    __syncthreads();
    // Hoist Q fragments (chunk-invariant). All waves hoist before any wave's
    // first Ps write (program order: hoist -> barrier1 -> stage -> barrier2).
    bf16x8 aq[2][2];
#pragma unroll
    for (int m = 0; m < 2; ++m) {
        aq[m][0] = *(const bf16x8*)(QPs + (wq + m * 16 + col) * LDP + fo);
        aq[m][1] = *(const bf16x8*)(QPs + (wq + m * 16 + col) * LDP + fo + 32);
    }

    // Fixed per-row softmax shift (provable bound modulo 12-sigma qk;
    // overshoot is still exact softmax).
    float mrow[2][4];
#pragma unroll
    for (int m = 0; m < 2; ++m)
#pragma unroll
        for (int r = 0; r < 4; ++r) {
            const int qpos = q0 + wq + m * 16 + rq + r;
            mrow[m][r] = slope * (float)(qpos < 128 ? qpos : 128) + 12.0f;
        }

    f32x4 o_acc[2][4] = {};
    float l_part[2][4] = {};

    const unsigned short* kbase  = qkvb + rowbase + 1024 + h * DK;
    const unsigned short* vbase0 = qkvb + rowbase + 2048 + h * DK;

    for (int c = 0; c < 3; ++c) {
        const int k0 = q0 - 128 + c * 128;
        __syncthreads();   // prev chunk's Ks/Vt/Ps reads done (c==0: after hoist)

        // --- K chunk via global_load_lds: 128 rows, 4 insts/wave ---
#pragma unroll
        for (int t = 0; t < 4; ++t) {
            const int rbase = w * 32 + t * 8;
            const unsigned short* gk = kbase + (long long)(k0 + rbase + srowK) * 3072 + schunkK;
            __builtin_amdgcn_global_load_lds(
                (const __attribute__((address_space(1))) void*)gk,
                (__attribute__((address_space(3))) void*)(Ks + rbase * 64), 16, 0, 0);
        }
        // --- V chunk (128 rows) transposed into Vt ---
#pragma unroll
        for (int e = 0; e < 2; ++e) {
            const int rp = tid >> 3;              // key pair 0..31
            const int cc = (tid & 7) * 8;         // d chunk
            const long long kk = (long long)(k0 + 64 * e + 2 * rp);
            const unsigned short* vb = vbase0 + cc;
            us8 v0 = *(const us8*)(vb + kk * 3072);
            us8 v1 = *(const us8*)(vb + (kk + 1) * 3072);
#pragma unroll
            for (int t = 0; t < 8; ++t) {
                unsigned pk = (unsigned)(unsigned short)v0[t] | ((unsigned)(unsigned short)v1[t] << 16);
                *(unsigned*)(Vt + (cc + t) * LDV2 + 64 * e + 2 * rp) = pk;
            }
        }
        __syncthreads();

        // --- QK^T: 32 MFMAs/wave -> S[q][key = j*16+col], j = 0..7 ---
        f32x4 sacc[2][8] = {};
#pragma unroll
        for (int j = 0; j < 8; ++j) {
            bf16x8 bk0 = *(const bf16x8*)(Ks + (j * 16 + col) * 64 + kc0);
            bf16x8 bk1 = *(const bf16x8*)(Ks + (j * 16 + col) * 64 + kc1);
#pragma unroll
            for (int m = 0; m < 2; ++m) {
                sacc[m][j] = __builtin_amdgcn_mfma_f32_16x16x32_bf16(aq[m][0], bk0, sacc[m][j], 0, 0, 0);
                sacc[m][j] = __builtin_amdgcn_mfma_f32_16x16x32_bf16(aq[m][1], bk1, sacc[m][j], 0, 0, 0);
            }
        }

        // --- bias + mask + exp(s - m_fixed); l partials; P -> Ps ---
#pragma unroll
        for (int m = 0; m < 2; ++m)
#pragma unroll
            for (int j = 0; j < 8; ++j) {
                const int kpos = k0 + j * 16 + col;
                const bool kin = (unsigned)kpos < (unsigned)S_LEN;
#pragma unroll
                for (int r = 0; r < 4; ++r) {
                    const int rel = (q0 + wq + m * 16 + rq + r) - kpos;
                    const bool ok = kin && (rel <= 128) && (rel >= -128);
                    float p = 0.f;
                    if (ok)
                        p = __expf(fmaf(sacc[m][j][r], 0.125f, slope * (float)rel - mrow[m][r]));
                    l_part[m][r] += p;
                    QPs[(wq + m * 16 + rq + r) * LDP2 + j * 16 + col] = f2bf(p);
                }
            }
        // no barrier: Ps rows [wq, wq+32) are wave-private

        // --- PV: 32 MFMAs/wave -> O[q][d = j4*16+col] ---
        {
            bf16x8 ap[2][4];
#pragma unroll
            for (int m = 0; m < 2; ++m)
#pragma unroll
                for (int t = 0; t < 4; ++t)
                    ap[m][t] = *(const bf16x8*)(QPs + (wq + m * 16 + col) * LDP2 + 32 * t + fo);
#pragma unroll
            for (int j4 = 0; j4 < 4; ++j4)
#pragma unroll
                for (int t = 0; t < 4; ++t) {
                    bf16x8 bv = *(const bf16x8*)(Vt + (j4 * 16 + col) * LDV2 + 32 * t + fo);
#pragma unroll
                    for (int m = 0; m < 2; ++m)
                        o_acc[m][j4] = __builtin_amdgcn_mfma_f32_16x16x32_bf16(ap[m][t], bv, o_acc[m][j4], 0, 0, 0);
                }
        }
    }

    // Epilogue: l reduction (16-lane butterfly) + bf16 store.
#pragma unroll
    for (int m = 0; m < 2; ++m) {
        float inv[4];
#pragma unroll
        for (int r = 0; r < 4; ++r) {
            float l = l_part[m][r];
#pragma unroll
            for (int off = 1; off < 16; off <<= 1) l += __shfl_xor(l, off, 64);
            inv[r] = 1.f / l;
        }
#pragma unroll
        for (int j4 = 0; j4 < 4; ++j4)
#pragma unroll
            for (int r = 0; r < 4; ++r) {
                const int qpos = q0 + wq + m * 16 + rq + r;
                aoutb[((size_t)b * S_LEN + qpos) * D_MODEL + h * DK + j4 * 16 + col] =
                    f2bf(o_acc[m][j4][r] * inv[r]);
            }
    }
}

// ---------------------------------------------------------------------------
extern "C" void kernel_launch(void* const* d_in, const int* in_sizes, int n_in,
                              void* d_out, int out_size, void* d_ws, size_t ws_size,
                              hipStream_t stream) {
    const float* x      = (const float*)d_in[0];
    const float* Wq     = (const float*)d_in[1];
    const float* Wk     = (const float*)d_in[2];
    const float* Wv     = (const float*)d_in[3];
    const float* Wo     = (const float*)d_in[4];
    const float* slopes = (const float*)d_in[5];
    float* out = (float*)d_out;

    unsigned short* xb    = (unsigned short*)d_ws;            // [4096,1024]
    unsigned short* wb    = xb    + (size_t)M_ROWS * D_MODEL; // [3072,1024] Wq|Wk|Wv
    unsigned short* wob   = wb    + (size_t)3072 * D_MODEL;   // [1024,1024]
    unsigned short* qkvb  = wob   + (size_t)1024 * D_MODEL;   // [4096,3072]
    unsigned short* aoutb = qkvb  + (size_t)M_ROWS * 3072;    // [4096,1024]

    dim3 blk(256);
    cvt_all<<<4096, blk, 0, stream>>>(x, Wq, Wk, Wv, Wo, xb);
    mfma_gemm_bt<1, 128><<<dim3(3072 / 128, M_ROWS / 128), blk, 0, stream>>>(xb, wb, qkvb, 3072);
    attn_mfma<<<dim3(NH, BATCH, S_LEN / QT), blk, 0, stream>>>(qkvb, slopes, aoutb);
    mfma_gemm_bt<0, 64><<<dim3(1024 / 64, M_ROWS / 128), blk, 0, stream>>>(aoutb, wob, out, 1024);
}

// Round 11
// 156.220 us; speedup vs baseline: 1.0259x; 1.0259x over previous
//
#include <hip/hip_runtime.h>
#include <hip/hip_bf16.h>

#define S_LEN   2048
#define D_MODEL 1024
#define NH      16
#define DK      64
#define BATCH   2
#define M_ROWS  (BATCH * S_LEN)   // 4096
#define LDP     72                // attn Q/Ps stride (bf16 elems)
#define LDV     66                // attn Vt stride (2-way writes = free)
#define LDW     132               // GEMM epilogue LDS stride

typedef __attribute__((ext_vector_type(8))) short bf16x8;
typedef __attribute__((ext_vector_type(4))) float f32x4;
typedef __attribute__((ext_vector_type(16))) float f32x16;
typedef __attribute__((ext_vector_type(8))) unsigned short us8;
typedef __attribute__((ext_vector_type(4))) unsigned short us4;

static __device__ __forceinline__ unsigned short f2bf(float f) {
    unsigned u = __builtin_bit_cast(unsigned, f);
    u += 0x7fffu + ((u >> 16) & 1u);   // RNE
    return (unsigned short)(u >> 16);
}

// ---------------------------------------------------------------------------
// All fp32->bf16 conversions in ONE launch. dst = xb | Wq | Wk | Wv | Wo.
// ---------------------------------------------------------------------------
__global__ __launch_bounds__(256) void cvt_all(const float* __restrict__ x,
                                               const float* __restrict__ wq,
                                               const float* __restrict__ wk,
                                               const float* __restrict__ wv,
                                               const float* __restrict__ wo,
                                               unsigned short* __restrict__ dst) {
    const int b = blockIdx.x;
    if (b < 2048) {
        const size_t o8 = (size_t)b * 256 + threadIdx.x;
        const float4* s = (const float4*)x + o8 * 2;
        float4 a = s[0], bb = s[1];
        us8 o;
        o[0] = f2bf(a.x);  o[1] = f2bf(a.y);  o[2] = f2bf(a.z);  o[3] = f2bf(a.w);
        o[4] = f2bf(bb.x); o[5] = f2bf(bb.y); o[6] = f2bf(bb.z); o[7] = f2bf(bb.w);
        *((us8*)dst + o8) = o;
    } else {
        const int wi = (b - 2048) >> 9;
        const float* src = (wi == 0) ? wq : (wi == 1) ? wk : (wi == 2) ? wv : wo;
        const size_t local = (size_t)((b - 2048) & 511) * 256 + threadIdx.x;
        const float4* s = (const float4*)src + local * 2;
        float4 a = s[0], bb = s[1];
        us8 o;
        o[0] = f2bf(a.x);  o[1] = f2bf(a.y);  o[2] = f2bf(a.z);  o[3] = f2bf(a.w);
        o[4] = f2bf(bb.x); o[5] = f2bf(bb.y); o[6] = f2bf(bb.z); o[7] = f2bf(bb.w);
        *((us8*)dst + 524288 + (size_t)wi * 131072 + local) = o;
    }
}

// ---------------------------------------------------------------------------
// MFMA GEMM (B-transposed): C[m,n] = sum_k A[m,k]*W[n,k], bf16 in, K=1024.
// ROUND-11: switched to mfma_f32_32x32x16_bf16 (m119: 2495 TF vs 2176 for
// 16x16x32 — ~15% faster pipe, half the MFMA instructions). Same XOR-swizzled
// global_load_lds staging; fragment rows keep row&7 == lane&7, so swizzled
// read offsets are 4 per-lane constants ((2s + (lane>>5)) ^ (lane&7))*8.
// C/D layout (verified m74/m101): col = lane&31, row = (reg&3)+8*(reg>>2)
// +4*(lane>>5).
// BN=128: 4 waves 2x2 of 64x64 (2x2 32-frags each), LDS bf16 epilogue.
// BN=64:  4 waves 32x64 (1x2 32-frags), direct fp32 stores (Wo, 2 blk/CU).
// ---------------------------------------------------------------------------
template <int STORE_BF16, int BN>
__global__ __launch_bounds__(256) void mfma_gemm_bt(const unsigned short* __restrict__ A,
                                                    const unsigned short* __restrict__ W,
                                                    void* __restrict__ Cv, int N) {
    constexpr int K = 1024, BM = 128, BK = 64;
    constexpr int MI = (BN == 128) ? 2 : 1;              // 32-row m-frags per wave
    constexpr int SMEM = (STORE_BF16 && BN == 128) ? (128 * LDW)
                                                   : (BM * BK + BN * BK);
    __shared__ unsigned short smem[SMEM];
    unsigned short* As = smem;               // [BM][BK]
    unsigned short* Bs = smem + BM * BK;     // [BN][BK]

    const int tid  = threadIdx.x;
    const int w    = tid >> 6;
    const int lane = tid & 63;
    const int m0 = blockIdx.y * BM;
    const int n0 = blockIdx.x * BN;
    const int wr = (BN == 128) ? (w >> 1) * 64 : w * 32;
    const int wc = (BN == 128) ? (w & 1) * 64 : 0;

    const int srow   = lane >> 3;                          // 0..7
    const int schunk = ((lane & 7) ^ (lane >> 3)) * 8;     // swizzled k-chunk (elems)
    const int l31   = lane & 31;
    const int khalf = lane >> 5;                           // 0/1
    const int sw    = lane & 7;
    int roff[4];
#pragma unroll
    for (int s = 0; s < 4; ++s)
        roff[s] = ((2 * s + khalf) ^ sw) * 8;              // kstep s read offset

    f32x16 acc[MI][2] = {};

    for (int k0 = 0; k0 < K; k0 += BK) {
        __syncthreads();
#pragma unroll
        for (int t = 0; t < 4; ++t) {                      // A: 16 groups, 4/wave
            const int rbase = w * 32 + t * 8;
            const unsigned short* ga = A + (size_t)(m0 + rbase + srow) * K + k0 + schunk;
            __builtin_amdgcn_global_load_lds(
                (const __attribute__((address_space(1))) void*)ga,
                (__attribute__((address_space(3))) void*)(As + rbase * BK), 16, 0, 0);
        }
#pragma unroll
        for (int t = 0; t < BN / 32; ++t) {                // B: wave stride BN/4
            const int rbase = w * (BN / 4) + t * 8;
            const unsigned short* gb = W + (size_t)(n0 + rbase + srow) * K + k0 + schunk;
            __builtin_amdgcn_global_load_lds(
                (const __attribute__((address_space(1))) void*)gb,
                (__attribute__((address_space(3))) void*)(Bs + rbase * BK), 16, 0, 0);
        }
        __syncthreads();

#pragma unroll
        for (int s = 0; s < 4; ++s) {                      // 4 ksteps of 16
            bf16x8 af[MI], bfr[2];
#pragma unroll
            for (int i = 0; i < MI; ++i)
                af[i] = *(const bf16x8*)(As + (wr + i * 32 + l31) * BK + roff[s]);
#pragma unroll
            for (int j = 0; j < 2; ++j)
                bfr[j] = *(const bf16x8*)(Bs + (wc + j * 32 + l31) * BK + roff[s]);
#pragma unroll
            for (int i = 0; i < MI; ++i)
#pragma unroll
                for (int j = 0; j < 2; ++j)
                    acc[i][j] = __builtin_amdgcn_mfma_f32_32x32x16_bf16(af[i], bfr[j], acc[i][j], 0, 0, 0);
        }
    }

    if constexpr (STORE_BF16 && BN == 128) {
        // C -> LDS (stride LDW) -> coalesced 16B stores.
        __syncthreads();
#pragma unroll
        for (int i = 0; i < 2; ++i)
#pragma unroll
            for (int j = 0; j < 2; ++j)
#pragma unroll
                for (int r = 0; r < 16; ++r) {
                    const int row_l = wr + i * 32 + (r & 3) + 8 * (r >> 2) + 4 * khalf;
                    const int col_l = wc + j * 32 + l31;
                    smem[row_l * LDW + col_l] = f2bf(acc[i][j][r]);
                }
        __syncthreads();
#pragma unroll
        for (int e = 0; e < 8; ++e) {
            const int idx = e * 256 + tid;
            const int row = idx >> 4;
            const int cc  = (idx & 15) * 8;
            us4 lo = *(const us4*)(smem + row * LDW + cc);
            us4 hi = *(const us4*)(smem + row * LDW + cc + 4);
            us8 v;
            v[0] = lo[0]; v[1] = lo[1]; v[2] = lo[2]; v[3] = lo[3];
            v[4] = hi[0]; v[5] = hi[1]; v[6] = hi[2]; v[7] = hi[3];
            *(us8*)((unsigned short*)Cv + (size_t)(m0 + row) * N + n0 + cc) = v;
        }
    } else {
#pragma unroll
        for (int i = 0; i < MI; ++i)
#pragma unroll
            for (int j = 0; j < 2; ++j)
#pragma unroll
                for (int r = 0; r < 16; ++r) {
                    const int gm = m0 + wr + i * 32 + (r & 3) + 8 * (r >> 2) + 4 * khalf;
                    const int gn = n0 + wc + j * 32 + l31;
                    if (STORE_BF16)
                        ((unsigned short*)Cv)[(size_t)gm * N + gn] = f2bf(acc[i][j][r]);
                    else
                        ((float*)Cv)[(size_t)gm * N + gn] = acc[i][j][r];
                }
    }
}

// ---------------------------------------------------------------------------
// MFMA sliding-window ALiBi attention — ROUND-9 version verbatim (fastest
// measured: 64-q tile, 5x64-key chunks, global_load_lds K with XOR swizzle,
// Vt stride 66, fixed-m softmax, Ps overlays Q buffer).
// ---------------------------------------------------------------------------
__global__ __launch_bounds__(256) void attn_mfma(const unsigned short* __restrict__ qkvb,
                                                 const float* __restrict__ slopes,
                                                 unsigned short* __restrict__ aoutb) {
    __shared__ unsigned short QPs[64 * LDP];  // Q staging, then reused as Ps
    __shared__ unsigned short Ks[64 * 64];    // unpadded, chunk-swizzled
    __shared__ unsigned short Vt[64 * LDV];   // [d][key]

    const int tid  = threadIdx.x;
    const int w    = tid >> 6;
    const int lane = tid & 63;
    const int q0 = blockIdx.x * 64;
    const int h  = blockIdx.y;
    const int b  = blockIdx.z;
    const float slope = slopes[h];
    const size_t rowbase = (size_t)b * S_LEN * 3072;

#pragma unroll
    for (int e = 0; e < 2; ++e) {
        int idx = e * 256 + tid;
        int r = idx >> 3, cc = (idx & 7) * 8;
        us8 v = *(const us8*)(qkvb + rowbase + (size_t)(q0 + r) * 3072 + h * DK + cc);
        *(us8*)(QPs + r * LDP + cc) = v;
    }

    const int col = lane & 15;
    const int rq  = (lane >> 4) * 4;
    const int wq  = w * 16;
    const int fo  = (lane >> 4) * 8;

    const int srowK   = lane >> 3;
    const int schunkK = ((lane & 7) ^ srowK) * 8;
    const int kc0 = (((lane >> 4) + 0) ^ (lane & 7)) * 8;
    const int kc1 = (((lane >> 4) + 4) ^ (lane & 7)) * 8;

    __syncthreads();
    const bf16x8 aq0 = *(const bf16x8*)(QPs + (wq + col) * LDP + fo);
    const bf16x8 aq1 = *(const bf16x8*)(QPs + (wq + col) * LDP + fo + 32);

    float mrow[4];
#pragma unroll
    for (int r = 0; r < 4; ++r) {
        const int qpos = q0 + wq + rq + r;
        mrow[r] = slope * (float)(qpos < 128 ? qpos : 128) + 12.0f;
    }

    f32x4 o_acc[4] = {};
    float l_part[4] = {0.f, 0.f, 0.f, 0.f};

    const unsigned short* kbase  = qkvb + rowbase + 1024 + h * DK;
    const unsigned short* vbase0 = qkvb + rowbase + 2048 + h * DK;

    for (int c = 0; c < 5; ++c) {
        const int k0 = q0 - 128 + c * 64;
        __syncthreads();

#pragma unroll
        for (int t = 0; t < 2; ++t) {
            const int rbase = w * 16 + t * 8;
            const unsigned short* gk = kbase + (long long)(k0 + rbase + srowK) * 3072 + schunkK;
            __builtin_amdgcn_global_load_lds(
                (const __attribute__((address_space(1))) void*)gk,
                (__attribute__((address_space(3))) void*)(Ks + rbase * 64), 16, 0, 0);
        }
        {
            const int rp = tid >> 3;
            const int cc = (tid & 7) * 8;
            const unsigned short* vb = vbase0 + cc;
            const long long kp0 = (long long)(k0 + rp * 2);
            us8 v0 = *(const us8*)(vb + kp0 * 3072);
            us8 v1 = *(const us8*)(vb + (kp0 + 1) * 3072);
#pragma unroll
            for (int t = 0; t < 8; ++t) {
                unsigned pk = (unsigned)(unsigned short)v0[t] | ((unsigned)(unsigned short)v1[t] << 16);
                *(unsigned*)(Vt + (cc + t) * LDV + rp * 2) = pk;
            }
        }
        __syncthreads();

        f32x4 sacc[4] = {};
#pragma unroll
        for (int j = 0; j < 4; ++j) {
            bf16x8 bk0 = *(const bf16x8*)(Ks + (j * 16 + col) * 64 + kc0);
            bf16x8 bk1 = *(const bf16x8*)(Ks + (j * 16 + col) * 64 + kc1);
            sacc[j] = __builtin_amdgcn_mfma_f32_16x16x32_bf16(aq0, bk0, sacc[j], 0, 0, 0);
            sacc[j] = __builtin_amdgcn_mfma_f32_16x16x32_bf16(aq1, bk1, sacc[j], 0, 0, 0);
        }

#pragma unroll
        for (int j = 0; j < 4; ++j) {
            const int kpos = k0 + j * 16 + col;
            const bool kin = (unsigned)kpos < (unsigned)S_LEN;
#pragma unroll
            for (int r = 0; r < 4; ++r) {
                const int rel = (q0 + wq + rq + r) - kpos;
                const bool ok = kin && (rel <= 128) && (rel >= -128);
                float p = 0.f;
                if (ok)
                    p = __expf(fmaf(sacc[j][r], 0.125f, slope * (float)rel - mrow[r]));
                l_part[r] += p;
                QPs[(wq + rq + r) * LDP + j * 16 + col] = f2bf(p);
            }
        }
        // no barrier: Ps rows [wq, wq+16) are wave-private

        {
            bf16x8 ap0 = *(const bf16x8*)(QPs + (wq + col) * LDP + fo);
            bf16x8 ap1 = *(const bf16x8*)(QPs + (wq + col) * LDP + fo + 32);
#pragma unroll
            for (int j = 0; j < 4; ++j) {
                bf16x8 bv0 = *(const bf16x8*)(Vt + (j * 16 + col) * LDV + fo);
                bf16x8 bv1 = *(const bf16x8*)(Vt + (j * 16 + col) * LDV + fo + 32);
                o_acc[j] = __builtin_amdgcn_mfma_f32_16x16x32_bf16(ap0, bv0, o_acc[j], 0, 0, 0);
                o_acc[j] = __builtin_amdgcn_mfma_f32_16x16x32_bf16(ap1, bv1, o_acc[j], 0, 0, 0);
            }
        }
    }

    float inv[4];
#pragma unroll
    for (int r = 0; r < 4; ++r) {
        float l = l_part[r];
#pragma unroll
        for (int off = 1; off < 16; off <<= 1) l += __shfl_xor(l, off, 64);
        inv[r] = 1.f / l;
    }

#pragma unroll
    for (int j = 0; j < 4; ++j)
#pragma unroll
        for (int r = 0; r < 4; ++r) {
            const int qpos = q0 + wq + rq + r;
            aoutb[((size_t)b * S_LEN + qpos) * D_MODEL + h * DK + j * 16 + col] =
                f2bf(o_acc[j][r] * inv[r]);
        }
}

// ---------------------------------------------------------------------------
extern "C" void kernel_launch(void* const* d_in, const int* in_sizes, int n_in,
                              void* d_out, int out_size, void* d_ws, size_t ws_size,
                              hipStream_t stream) {
    const float* x      = (const float*)d_in[0];
    const float* Wq     = (const float*)d_in[1];
    const float* Wk     = (const float*)d_in[2];
    const float* Wv     = (const float*)d_in[3];
    const float* Wo     = (const float*)d_in[4];
    const float* slopes = (const float*)d_in[5];
    float* out = (float*)d_out;

    unsigned short* xb    = (unsigned short*)d_ws;            // [4096,1024]
    unsigned short* wb    = xb    + (size_t)M_ROWS * D_MODEL; // [3072,1024] Wq|Wk|Wv
    unsigned short* wob   = wb    + (size_t)3072 * D_MODEL;   // [1024,1024]
    unsigned short* qkvb  = wob   + (size_t)1024 * D_MODEL;   // [4096,3072]
    unsigned short* aoutb = qkvb  + (size_t)M_ROWS * 3072;    // [4096,1024]

    dim3 blk(256);
    cvt_all<<<4096, blk, 0, stream>>>(x, Wq, Wk, Wv, Wo, xb);
    mfma_gemm_bt<1, 128><<<dim3(3072 / 128, M_ROWS / 128), blk, 0, stream>>>(xb, wb, qkvb, 3072);
    attn_mfma<<<dim3(S_LEN / 64, NH, BATCH), blk, 0, stream>>>(qkvb, slopes, aoutb);
    mfma_gemm_bt<0, 64><<<dim3(1024 / 64, M_ROWS / 128), blk, 0, stream>>>(aoutb, wob, out, 1024);
}